// Round 1
// baseline (3284.219 us; speedup 1.0000x reference)
//
#include <hip/hip_runtime.h>
#include <hip/hip_bf16.h>
#include <stdint.h>

#define DEV __device__ __forceinline__

typedef float f32x4 __attribute__((ext_vector_type(4)));
typedef short bf16x8 __attribute__((ext_vector_type(8)));
typedef short bf16x4 __attribute__((ext_vector_type(4)));

#define NH 24
#define DH 128
#define DMODEL 3072
#define LTXT 512
#define LIMG 1024
#define LTOT 1536
#define N1 21504
#define QKVD 9216
#define N2CAT 15360

DEV unsigned short f2bfu(float f) {
    __hip_bfloat16 b = __float2bfloat16(f);
    unsigned short s;
    __builtin_memcpy(&s, &b, 2);
    return s;
}
DEV float bfu2f(unsigned int u) {  // low 16 bits = bf16
    return __uint_as_float(u << 16);
}

DEV void gld_lds16(const void* g, void* l) {
    __builtin_amdgcn_global_load_lds(
        (const __attribute__((address_space(1))) unsigned int*)g,
        (__attribute__((address_space(3))) unsigned int*)l, 16, 0, 0);
}

// ---------------- K1: mod = silu(vec) @ mod_w^T + mod_b ----------------
__global__ __launch_bounds__(256) void mod_gemv_kernel(
    const float* __restrict__ vec, const float* __restrict__ mw,
    const float* __restrict__ mb, float* __restrict__ modv)
{
    __shared__ float sv[3072];
    int tid = threadIdx.x;
    for (int i = tid; i < 768; i += 256) {
        float4 x = ((const float4*)vec)[i];
        float4 y;
        y.x = x.x / (1.f + __expf(-x.x));
        y.y = x.y / (1.f + __expf(-x.y));
        y.z = x.z / (1.f + __expf(-x.z));
        y.w = x.w / (1.f + __expf(-x.w));
        ((float4*)sv)[i] = y;
    }
    __syncthreads();
    int row = blockIdx.x * 4 + (tid >> 6);
    int lane = tid & 63;
    const float* wr = mw + (size_t)row * 3072;
    float s = 0.f;
    for (int i = lane; i < 768; i += 64) {
        float4 w = ((const float4*)wr)[i];
        float4 x = ((const float4*)sv)[i];
        s += w.x * x.x + w.y * x.y + w.z * x.z + w.w * x.w;
    }
#pragma unroll
    for (int d = 1; d < 64; d <<= 1) s += __shfl_xor(s, d);
    if (lane == 0) modv[row] = s + mb[row];
}

// ---------------- K2: LayerNorm + modulation -> x_mod (bf16) ----------------
__global__ __launch_bounds__(256) void ln_mod_kernel(
    const float* __restrict__ txt, const float* __restrict__ img,
    const float* __restrict__ modv, unsigned short* __restrict__ xmod)
{
    int l = blockIdx.x, tid = threadIdx.x;
    const float* xr = (l < LTXT) ? txt + (size_t)l * 3072 : img + (size_t)(l - LTXT) * 3072;
    float4 v[3];
    float s = 0.f;
#pragma unroll
    for (int j = 0; j < 3; ++j) {
        v[j] = ((const float4*)xr)[tid + 256 * j];
        s += v[j].x + v[j].y + v[j].z + v[j].w;
    }
    __shared__ float red[4];
#pragma unroll
    for (int d = 1; d < 64; d <<= 1) s += __shfl_xor(s, d);
    if ((tid & 63) == 0) red[tid >> 6] = s;
    __syncthreads();
    float mean = (red[0] + red[1] + red[2] + red[3]) * (1.f / 3072.f);
    __syncthreads();
    float s2 = 0.f;
#pragma unroll
    for (int j = 0; j < 3; ++j) {
        float dx = v[j].x - mean, dy = v[j].y - mean, dz = v[j].z - mean, dw = v[j].w - mean;
        s2 += dx * dx + dy * dy + dz * dz + dw * dw;
    }
#pragma unroll
    for (int d = 1; d < 64; d <<= 1) s2 += __shfl_xor(s2, d);
    if ((tid & 63) == 0) red[tid >> 6] = s2;
    __syncthreads();
    float var = (red[0] + red[1] + red[2] + red[3]) * (1.f / 3072.f);
    float rstd = rsqrtf(var + 1e-6f);
#pragma unroll
    for (int j = 0; j < 3; ++j) {
        int i = tid + 256 * j;
        int c = 4 * i;
        float o0 = (1.f + modv[3072 + c + 0]) * ((v[j].x - mean) * rstd) + modv[c + 0];
        float o1 = (1.f + modv[3072 + c + 1]) * ((v[j].y - mean) * rstd) + modv[c + 1];
        float o2 = (1.f + modv[3072 + c + 2]) * ((v[j].z - mean) * rstd) + modv[c + 2];
        float o3 = (1.f + modv[3072 + c + 3]) * ((v[j].w - mean) * rstd) + modv[c + 3];
        uint2 pk;
        pk.x = (unsigned)f2bfu(o0) | ((unsigned)f2bfu(o1) << 16);
        pk.y = (unsigned)f2bfu(o2) | ((unsigned)f2bfu(o3) << 16);
        ((uint2*)(xmod + (size_t)l * 3072))[i] = pk;
    }
}

// ---------------- GEMM: C = A(bf16, MxK) * W(f32, NxK)^T + bias ----------------
// MODE 0: N=21504 -> cols<9216 raw to yqkv; cols>=9216 gelu -> a2[:,3072+...]
// MODE 1: N=3072  -> out = x + gate*(C+bias), img rows first in dout, then txt
template <int BN, int MODE>
__global__ __launch_bounds__(256, 2) void gemm_kernel(
    const unsigned short* __restrict__ A, const float* __restrict__ W,
    const float* __restrict__ bias, int K,
    unsigned short* __restrict__ out_qkv, unsigned short* __restrict__ out_a2,
    const float* __restrict__ txt, const float* __restrict__ img,
    const float* __restrict__ modv, float* __restrict__ dout)
{
    constexpr int WN = BN / 2;
    constexpr int NI = BN / 32;
    __shared__ unsigned short sA[128 * 64];
    __shared__ float sB[BN * 64];
    const int tid = threadIdx.x;
    const int wave = tid >> 6, lane = tid & 63;
    const int r16 = lane & 15, g4 = lane >> 4;
    const int m0 = blockIdx.x * 128, n0 = blockIdx.y * BN;
    const int wm = (wave >> 1) * 64, wn = (wave & 1) * WN;

    f32x4 zero = {0.f, 0.f, 0.f, 0.f};
    f32x4 acc[4][NI];
#pragma unroll
    for (int i = 0; i < 4; ++i)
#pragma unroll
        for (int j = 0; j < NI; ++j) acc[i][j] = zero;

    const unsigned short* aSrc = A + (size_t)(m0 + wave * 32 + (lane >> 3)) * K + (lane & 7) * 8;
    const float* bSrc = W + (size_t)(n0 + wave * (BN / 4) + (lane >> 4)) * K + (lane & 15) * 4;
    char* sAb = (char*)sA;
    char* sBb = (char*)sB;
    char* aDst = sAb + wave * 4 * 1024;
    char* bDst = sBb + wave * (BN / 16) * 1024;

    for (int kt = 0; kt < K; kt += 64) {
#pragma unroll
        for (int j = 0; j < 4; ++j) gld_lds16(aSrc + (size_t)j * 8 * K, aDst + j * 1024);
#pragma unroll
        for (int j = 0; j < BN / 16; ++j) gld_lds16(bSrc + (size_t)j * 4 * K, bDst + j * 1024);
        aSrc += 64;
        bSrc += 64;
        __syncthreads();
#pragma unroll
        for (int ks = 0; ks < 2; ++ks) {
            bf16x8 af[4];
#pragma unroll
            for (int i = 0; i < 4; ++i)
                af[i] = *(const bf16x8*)(sAb + (wm + i * 16 + r16) * 128 + ks * 64 + g4 * 16);
            bf16x8 bfr[NI];
#pragma unroll
            for (int j = 0; j < NI; ++j) {
                const float* p = (const float*)(sBb + (wn + j * 16 + r16) * 256 + ks * 128 + g4 * 32);
                float4 x0 = *(const float4*)p;
                float4 x1 = *(const float4*)(p + 4);
                bf16x8 t;
                t[0] = (short)f2bfu(x0.x); t[1] = (short)f2bfu(x0.y);
                t[2] = (short)f2bfu(x0.z); t[3] = (short)f2bfu(x0.w);
                t[4] = (short)f2bfu(x1.x); t[5] = (short)f2bfu(x1.y);
                t[6] = (short)f2bfu(x1.z); t[7] = (short)f2bfu(x1.w);
                bfr[j] = t;
            }
#pragma unroll
            for (int i = 0; i < 4; ++i)
#pragma unroll
                for (int j = 0; j < NI; ++j)
                    acc[i][j] = __builtin_amdgcn_mfma_f32_16x16x32_bf16(af[i], bfr[j], acc[i][j], 0, 0, 0);
        }
        __syncthreads();
    }

    if (MODE == 0) {
        const bool qkvreg = (n0 < QKVD);
#pragma unroll
        for (int i = 0; i < 4; ++i)
#pragma unroll
            for (int j = 0; j < NI; ++j) {
                int n = n0 + wn + j * 16 + r16;
                float bv = bias[n];
#pragma unroll
                for (int r = 0; r < 4; ++r) {
                    int m = m0 + wm + i * 16 + g4 * 4 + r;
                    float v = acc[i][j][r] + bv;
                    if (qkvreg) {
                        out_qkv[(size_t)m * QKVD + n] = f2bfu(v);
                    } else {
                        float t = 0.7978845608028654f * (v + 0.044715f * v * v * v);
                        float th = 1.f - 2.f / (__expf(2.f * t) + 1.f);
                        float gl = 0.5f * v * (1.f + th);
                        out_a2[(size_t)m * N2CAT + 3072 + (n - QKVD)] = f2bfu(gl);
                    }
                }
            }
    } else {
#pragma unroll
        for (int i = 0; i < 4; ++i)
#pragma unroll
            for (int j = 0; j < NI; ++j) {
                int n = n0 + wn + j * 16 + r16;
                float bv = bias[n];
                float gate = modv[6144 + n];
#pragma unroll
                for (int r = 0; r < 4; ++r) {
                    int m = m0 + wm + i * 16 + g4 * 4 + r;
                    float v = acc[i][j][r] + bv;
                    float xv = (m < LTXT) ? txt[(size_t)m * 3072 + n]
                                          : img[(size_t)(m - LTXT) * 3072 + n];
                    float o = xv + gate * v;
                    if (m < LTXT)
                        dout[(size_t)LIMG * 3072 + (size_t)m * 3072 + n] = o;
                    else
                        dout[(size_t)(m - LTXT) * 3072 + n] = o;
                }
            }
    }
}

// ---------------- K4: qkv -> rmsnorm+rope q,k ; v transposed ----------------
__global__ __launch_bounds__(256) void qkv_prep_kernel(
    const unsigned short* __restrict__ yqkv,
    const float* __restrict__ txt_pe, const float* __restrict__ img_pe,
    const float* __restrict__ qs, const float* __restrict__ ksc,
    unsigned short* __restrict__ qn, unsigned short* __restrict__ kn,
    unsigned short* __restrict__ vT)
{
    int h = blockIdx.x, l0 = blockIdx.y * 32;
    int wave = threadIdx.x >> 6, lane = threadIdx.x & 63;
    __shared__ unsigned short vtile[32][128];
#pragma unroll
    for (int rr = 0; rr < 8; ++rr) {
        int lr = wave * 8 + rr;
        int l = l0 + lr;
        const unsigned short* base = yqkv + (size_t)l * QKVD + h * DH + 2 * lane;
        unsigned int qu = *(const unsigned int*)base;
        unsigned int ku = *(const unsigned int*)(base + 3072);
        unsigned int vu = *(const unsigned int*)(base + 6144);
        float q0 = bfu2f(qu & 0xffffu), q1 = bfu2f(qu >> 16);
        float k0 = bfu2f(ku & 0xffffu), k1 = bfu2f(ku >> 16);
        float sq = q0 * q0 + q1 * q1, sk = k0 * k0 + k1 * k1;
#pragma unroll
        for (int d = 1; d < 64; d <<= 1) {
            sq += __shfl_xor(sq, d);
            sk += __shfl_xor(sk, d);
        }
        float rq = rsqrtf(sq * (1.f / 128.f) + 1e-6f);
        float rk = rsqrtf(sk * (1.f / 128.f) + 1e-6f);
        float qa = q0 * rq * qs[2 * lane], qb = q1 * rq * qs[2 * lane + 1];
        float ka = k0 * rk * ksc[2 * lane], kb = k1 * rk * ksc[2 * lane + 1];
        const float* pe = ((l < LTXT) ? txt_pe + (size_t)l * 256
                                      : img_pe + (size_t)(l - LTXT) * 256) + lane * 4;
        float4 p = *(const float4*)pe;
        float qo0 = p.x * qa + p.y * qb, qo1 = p.z * qa + p.w * qb;
        float ko0 = p.x * ka + p.y * kb, ko1 = p.z * ka + p.w * kb;
        size_t off = ((size_t)h * LTOT + l) * DH + 2 * lane;
        *(unsigned int*)(qn + off) = (unsigned)f2bfu(qo0) | ((unsigned)f2bfu(qo1) << 16);
        *(unsigned int*)(kn + off) = (unsigned)f2bfu(ko0) | ((unsigned)f2bfu(ko1) << 16);
        *(unsigned int*)(&vtile[lr][2 * lane]) = vu;
    }
    __syncthreads();
    int d = threadIdx.x >> 1, half = threadIdx.x & 1;
    union { unsigned short h2[16]; int4 v2[2]; } u;
#pragma unroll
    for (int j = 0; j < 16; ++j) u.h2[j] = vtile[half * 16 + j][d];
    int4* dst = (int4*)(vT + ((size_t)h * DH + d) * LTOT + l0 + half * 16);
    dst[0] = u.v2[0];
    dst[1] = u.v2[1];
}

// ---------------- K5: flash attention ----------------
__global__ __launch_bounds__(256) void attn_kernel(
    const unsigned short* __restrict__ qn, const unsigned short* __restrict__ kn,
    const unsigned short* __restrict__ vT, unsigned short* __restrict__ a2o)
{
    int h = blockIdx.x, qt = blockIdx.y;
    int wave = threadIdx.x >> 6, lane = threadIdx.x & 63;
    int r16 = lane & 15, g4 = lane >> 4;
    int q0 = qt * 64 + wave * 16;
    const unsigned short* Qb = qn + (size_t)h * LTOT * DH;
    const unsigned short* Kb = kn + (size_t)h * LTOT * DH;
    const unsigned short* Vb = vT + (size_t)h * DH * LTOT;
    bf16x4 qf[8];
#pragma unroll
    for (int kk = 0; kk < 8; ++kk)
        qf[kk] = *(const bf16x4*)(Qb + (size_t)(q0 + r16) * DH + kk * 16 + 4 * g4);
    f32x4 zero = {0.f, 0.f, 0.f, 0.f};
    f32x4 acc[8];
#pragma unroll
    for (int dt = 0; dt < 8; ++dt) acc[dt] = zero;
    float mrun = -1e30f, lrun = 0.f;
    const float sc = 0.08838834764831843f;
    for (int kt = 0; kt < 96; ++kt) {
        f32x4 st = {0.f, 0.f, 0.f, 0.f};
#pragma unroll
        for (int kk = 0; kk < 8; ++kk) {
            bf16x4 kf = *(const bf16x4*)(Kb + (size_t)(kt * 16 + r16) * DH + kk * 16 + 4 * g4);
            st = __builtin_amdgcn_mfma_f32_16x16x16bf16_1k(kf, qf[kk], st, 0, 0, 0);
        }
        float s0 = st[0] * sc, s1 = st[1] * sc, s2 = st[2] * sc, s3 = st[3] * sc;
        float tmax = fmaxf(fmaxf(s0, s1), fmaxf(s2, s3));
        tmax = fmaxf(tmax, __shfl_xor(tmax, 16));
        tmax = fmaxf(tmax, __shfl_xor(tmax, 32));
        float mnew = fmaxf(mrun, tmax);
        float alpha = __expf(mrun - mnew);
        float p0 = __expf(s0 - mnew), p1 = __expf(s1 - mnew);
        float p2 = __expf(s2 - mnew), p3 = __expf(s3 - mnew);
        float ts = p0 + p1 + p2 + p3;
        ts += __shfl_xor(ts, 16);
        ts += __shfl_xor(ts, 32);
        lrun = lrun * alpha + ts;
        mrun = mnew;
        float a0 = __shfl(alpha, g4 * 4 + 0), a1 = __shfl(alpha, g4 * 4 + 1);
        float a2v = __shfl(alpha, g4 * 4 + 2), a3 = __shfl(alpha, g4 * 4 + 3);
        f32x4 am = {a0, a1, a2v, a3};
        bf16x4 pa;
        pa[0] = (short)f2bfu(p0); pa[1] = (short)f2bfu(p1);
        pa[2] = (short)f2bfu(p2); pa[3] = (short)f2bfu(p3);
#pragma unroll
        for (int dt = 0; dt < 8; ++dt) {
            bf16x4 vf = *(const bf16x4*)(Vb + (size_t)(dt * 16 + r16) * LTOT + kt * 16 + 4 * g4);
            acc[dt] = acc[dt] * am;
            acc[dt] = __builtin_amdgcn_mfma_f32_16x16x16bf16_1k(pa, vf, acc[dt], 0, 0, 0);
        }
    }
    float l0v = __shfl(lrun, g4 * 4 + 0), l1v = __shfl(lrun, g4 * 4 + 1);
    float l2v = __shfl(lrun, g4 * 4 + 2), l3v = __shfl(lrun, g4 * 4 + 3);
    f32x4 linv = {1.f / l0v, 1.f / l1v, 1.f / l2v, 1.f / l3v};
#pragma unroll
    for (int dt = 0; dt < 8; ++dt) {
#pragma unroll
        for (int r = 0; r < 4; ++r) {
            float val = acc[dt][r] * linv[r];
            a2o[(size_t)(q0 + 4 * g4 + r) * N2CAT + h * DH + dt * 16 + r16] = f2bfu(val);
        }
    }
}

extern "C" void kernel_launch(void* const* d_in, const int* in_sizes, int n_in,
                              void* d_out, int out_size, void* d_ws, size_t ws_size,
                              hipStream_t stream) {
    const float* img = (const float*)d_in[0];
    const float* txt = (const float*)d_in[1];
    const float* vec = (const float*)d_in[2];
    const float* txt_pe = (const float*)d_in[3];
    const float* img_pe = (const float*)d_in[4];
    const float* w1 = (const float*)d_in[5];
    const float* b1 = (const float*)d_in[6];
    const float* w2 = (const float*)d_in[7];
    const float* b2 = (const float*)d_in[8];
    const float* mw = (const float*)d_in[9];
    const float* mb = (const float*)d_in[10];
    const float* qs = (const float*)d_in[11];
    const float* ksc = (const float*)d_in[12];
    float* dout = (float*)d_out;
    char* ws = (char*)d_ws;

    float* modv = (float*)ws;                                   // 9216 f32
    unsigned short* xmod = (unsigned short*)(ws + 36864);       // 1536x3072 bf16
    unsigned short* yqkv = (unsigned short*)(ws + 9474048);     // 1536x9216 bf16
    unsigned short* a2 = (unsigned short*)(ws + 37785600);      // 1536x15360 bf16
    unsigned short* qn = (unsigned short*)(ws + 84971520);      // 24x1536x128 bf16
    unsigned short* kn = (unsigned short*)(ws + 94408704);
    unsigned short* vT = (unsigned short*)(ws + 103845888);     // ends ~113MB

    hipLaunchKernelGGL(mod_gemv_kernel, dim3(2304), dim3(256), 0, stream, vec, mw, mb, modv);
    hipLaunchKernelGGL(ln_mod_kernel, dim3(1536), dim3(256), 0, stream, txt, img, modv, xmod);
    hipLaunchKernelGGL((gemm_kernel<128, 0>), dim3(12, 168), dim3(256), 0, stream,
                       xmod, w1, b1, 3072, yqkv, a2,
                       (const float*)nullptr, (const float*)nullptr, (const float*)nullptr, (float*)nullptr);
    hipLaunchKernelGGL(qkv_prep_kernel, dim3(24, 48), dim3(256), 0, stream,
                       yqkv, txt_pe, img_pe, qs, ksc, qn, kn, vT);
    hipLaunchKernelGGL(attn_kernel, dim3(24, 24), dim3(256), 0, stream, qn, kn, vT, a2);
    hipLaunchKernelGGL((gemm_kernel<64, 1>), dim3(12, 48), dim3(256), 0, stream,
                       a2, w2, b2, 15360,
                       (unsigned short*)nullptr, (unsigned short*)nullptr, txt, img, modv, dout);
}